// Round 2
// baseline (1309.046 us; speedup 1.0000x reference)
//
#include <hip/hip_runtime.h>
#include <math.h>

// S4 DPLR forward: evaluated -> ifft -> K ; y = irfft(rfft(u)*rfft(K)) + D*u
// Sizes fixed by the problem: B=4, L=16384, D=512, N=64. n_fft=2L=32768.
// All FFTs are half-length (16384) complex via real-packing, batched along the
// contiguous d axis (Stockham, no transposes, coalesced across d).
//
// Round-1 lesson: __sincosf maps to v_sin/v_cos (revolutions-scaled). At
// ang=-pi the scaled arg rounds to exactly -0.5 -> sin returns exactly -0.0,
// making 1+Omega exactly (0,0) at l=8192 -> cdiv NaN -> NaN everywhere.
// k_ev now uses accurate sincosf. FFT twiddles keep __sincosf (angles are
// j/(pR) < 1/4 revolutions; exact-collapse only at j=0 where (1,0) is
// correct, and nothing divides by them).

#define D_DIM 512
#define NFFT 16384            // half-length complex FFT size
#define NMODE 64
#define TWO_PI_F 6.283185307179586f
#define PI_F 3.14159265358979323846f

struct C2 { float x, y; };

__device__ __forceinline__ C2 cmul(C2 a, C2 b){ return C2{a.x*b.x - a.y*b.y, a.x*b.y + a.y*b.x}; }
__device__ __forceinline__ C2 cadd(C2 a, C2 b){ return C2{a.x+b.x, a.y+b.y}; }
__device__ __forceinline__ C2 csub(C2 a, C2 b){ return C2{a.x-b.x, a.y-b.y}; }
__device__ __forceinline__ C2 cdiv(C2 a, C2 b){
  float inv = 1.f/(b.x*b.x + b.y*b.y);
  return C2{(a.x*b.x + a.y*b.y)*inv, (a.y*b.x - a.x*b.y)*inv};
}
__device__ __forceinline__ void cfma_(C2& acc, C2 a, C2 b){
  acc.x = fmaf(a.x, b.x, fmaf(-a.y, b.y, acc.x));
  acc.y = fmaf(a.x, b.y, fmaf( a.y, b.x, acc.y));
}

// DFT-4, sign = e^{-2pi i/4} for fwd (INV=false), e^{+} for inverse.
template<bool INV>
__device__ __forceinline__ void dft4(C2& a, C2& b, C2& c, C2& d){
  C2 t0 = cadd(a,c), t1 = csub(a,c), t2 = cadd(b,d), t3 = csub(b,d);
  C2 it3 = INV ? C2{-t3.y, t3.x} : C2{t3.y, -t3.x};   // +/- i*t3
  a = cadd(t0,t2); c = csub(t0,t2); b = cadd(t1,it3); d = csub(t1,it3);
}

template<bool INV>
__device__ __forceinline__ void twd(C2& v, float c, float s){
  C2 w{c, INV ? s : -s};
  v = cmul(v, w);
}

// In-place 16-point DFT (DIT 4x4). Output X[s] lives at v[perm16(s)] where
// perm16(s) = 4*(s&3) + (s>>2).
template<bool INV>
__device__ __forceinline__ void dft16(C2 v[16]){
  dft4<INV>(v[0], v[4], v[8],  v[12]);
  dft4<INV>(v[1], v[5], v[9],  v[13]);
  dft4<INV>(v[2], v[6], v[10], v[14]);
  dft4<INV>(v[3], v[7], v[11], v[15]);
  const float C1 = 0.9238795325112867f, S1 = 0.3826834323650898f;
  const float CQ = 0.7071067811865476f;
  const float C3 = 0.3826834323650898f, S3 = 0.9238795325112867f;
  twd<INV>(v[5],  C1,  S1);   // W16^1
  twd<INV>(v[9],  CQ,  CQ);   // W16^2
  twd<INV>(v[13], C3,  S3);   // W16^3
  twd<INV>(v[6],  CQ,  CQ);   // W16^2
  twd<INV>(v[10], 0.f, 1.f);  // W16^4
  twd<INV>(v[14], -CQ, CQ);   // W16^6
  twd<INV>(v[7],  C3,  S3);   // W16^3
  twd<INV>(v[11], -CQ, CQ);   // W16^6
  twd<INV>(v[15], -C1, -S1);  // W16^9
  dft4<INV>(v[0],  v[1],  v[2],  v[3]);
  dft4<INV>(v[4],  v[5],  v[6],  v[7]);
  dft4<INV>(v[8],  v[9],  v[10], v[11]);
  dft4<INV>(v[12], v[13], v[14], v[15]);
}

// ---------------- generic Stockham radix-16 pass (batched over d, b) -------
template<bool INV>
__global__ __launch_bounds__(256) void k_pass16(const C2* __restrict__ in, C2* __restrict__ out,
                                                int p, long long bstride){
  int idx = blockIdx.x*256 + threadIdx.x;       // [0, 1024*512)
  int d = idx & (D_DIM-1);
  int t = idx >> 9;                              // [0, 1024)
  const C2* ib = in  + (long long)blockIdx.y * bstride;
  C2*       ob = out + (long long)blockIdx.y * bstride;
  C2 v[16];
  #pragma unroll
  for (int s=0;s<16;s++) v[s] = ib[(long long)(t + s*1024)*D_DIM + d];
  int j = t & (p-1);
  if (p > 1){
    float th = (INV ? TWO_PI_F : -TWO_PI_F) * (float)j / (float)(p*16);
    float sn, cs; __sincosf(th, &sn, &cs);
    C2 w1{cs, sn};
    C2 w = w1;
    v[1] = cmul(v[1], w);
    #pragma unroll
    for (int s=2;s<16;s++){ w = cmul(w, w1); v[s] = cmul(v[s], w); }
  }
  dft16<INV>(v);
  int base = ((t - j) << 4) + j;
  #pragma unroll
  for (int s=0;s<16;s++){
    int pidx = ((s&3)<<2) | (s>>2);              // perm16(s)
    ob[(long long)(base + s*p)*D_DIM + d] = v[pidx];
  }
}

// -------- first forward pass fused with real->packed-complex zero-pad ------
// z[r] = src[2r] + i*src[2r+1] for r<8192, else 0. p=1, radix-16, fwd sign.
__global__ __launch_bounds__(256) void k_pass16_first(const float* __restrict__ src, C2* __restrict__ out,
                                                      long long src_bstride, long long out_bstride){
  int idx = blockIdx.x*256 + threadIdx.x;
  int d = idx & (D_DIM-1);
  int t = idx >> 9;
  const float* sb = src + (long long)blockIdx.y * src_bstride;
  C2*          ob = out + (long long)blockIdx.y * out_bstride;
  C2 v[16];
  #pragma unroll
  for (int s=0;s<8;s++){
    long long r = t + s*1024;                    // < 8192 always
    v[s].x = sb[(2*r)  *D_DIM + d];
    v[s].y = sb[(2*r+1)*D_DIM + d];
  }
  #pragma unroll
  for (int s=8;s<16;s++) v[s] = C2{0.f, 0.f};
  dft16<false>(v);
  int base = t << 4;
  #pragma unroll
  for (int s=0;s<16;s++){
    int pidx = ((s&3)<<2) | (s>>2);
    ob[(long long)(base + s)*D_DIM + d] = v[pidx];
  }
}

// ---------------- generic Stockham radix-4 pass ----------------------------
template<bool INV>
__global__ __launch_bounds__(256) void k_pass4(const C2* __restrict__ in, C2* __restrict__ out,
                                               int p, long long bstride){
  int idx = blockIdx.x*256 + threadIdx.x;        // [0, 4096*512)
  int d = idx & (D_DIM-1);
  int t = idx >> 9;                               // [0, 4096)
  const C2* ib = in  + (long long)blockIdx.y * bstride;
  C2*       ob = out + (long long)blockIdx.y * bstride;
  C2 v[4];
  #pragma unroll
  for (int s=0;s<4;s++) v[s] = ib[(long long)(t + s*4096)*D_DIM + d];
  int j = t & (p-1);
  if (p > 1){
    float th = (INV ? TWO_PI_F : -TWO_PI_F) * (float)j / (float)(p*4);
    float sn, cs; __sincosf(th, &sn, &cs);
    C2 w1{cs, sn};
    v[1] = cmul(v[1], w1);
    C2 w2 = cmul(w1, w1);
    v[2] = cmul(v[2], w2);
    v[3] = cmul(v[3], cmul(w2, w1));
  }
  dft4<INV>(v[0], v[1], v[2], v[3]);
  int base = ((t - j) << 2) + j;
  #pragma unroll
  for (int s=0;s<4;s++) ob[(long long)(base + s*p)*D_DIM + d] = v[s];
}

// ---- last inverse pass of the K-ifft: write real part only (K kernel) -----
// p=4096, radix-4, INV sign. Scale 1/L is already folded into `evaluated`.
__global__ __launch_bounds__(256) void k_pass4_lastreal(const C2* __restrict__ in, float* __restrict__ outr){
  int idx = blockIdx.x*256 + threadIdx.x;
  int d = idx & (D_DIM-1);
  int t = idx >> 9;                               // [0,4096)
  C2 v[4];
  #pragma unroll
  for (int s=0;s<4;s++) v[s] = in[(long long)(t + s*4096)*D_DIM + d];
  float th = TWO_PI_F * (float)t / 16384.f;       // j=t, p*r=16384
  float sn, cs; __sincosf(th, &sn, &cs);
  C2 w1{cs, sn};
  v[1] = cmul(v[1], w1);
  C2 w2 = cmul(w1, w1);
  v[2] = cmul(v[2], w2);
  v[3] = cmul(v[3], cmul(w2, w1));
  dft4<true>(v[0], v[1], v[2], v[3]);
  #pragma unroll
  for (int s=0;s<4;s++) outr[(long long)(t + s*4096)*D_DIM + d] = v[s].x;
}

// ---- last inverse pass of u-path: unpack y=Re/Im, scale 1/N, + D*u --------
__global__ __launch_bounds__(256) void k_pass4_lastyfused(const C2* __restrict__ in,
                                                          const float* __restrict__ u,
                                                          const float* __restrict__ Dp,
                                                          float* __restrict__ y,
                                                          long long cbstride, long long rbstride){
  int idx = blockIdx.x*256 + threadIdx.x;
  int d = idx & (D_DIM-1);
  int t = idx >> 9;                               // [0,4096)
  const C2* ib   = in + (long long)blockIdx.y * cbstride;
  const float* ub = u + (long long)blockIdx.y * rbstride;
  float*       yb = y + (long long)blockIdx.y * rbstride;
  C2 v[4];
  #pragma unroll
  for (int s=0;s<4;s++) v[s] = ib[(long long)(t + s*4096)*D_DIM + d];
  float th = TWO_PI_F * (float)t / 16384.f;
  float sn, cs; __sincosf(th, &sn, &cs);
  C2 w1{cs, sn};
  v[1] = cmul(v[1], w1);
  C2 w2 = cmul(w1, w1);
  v[2] = cmul(v[2], w2);
  v[3] = cmul(v[3], cmul(w2, w1));
  dft4<true>(v[0], v[1], v[2], v[3]);
  float dp = Dp[0];
  const float invN = 1.f/16384.f;
  // outputs t + s*4096: only s<2 fall in [0,8192) -> y rows [0,16384)
  #pragma unroll
  for (int s=0;s<2;s++){
    long long r = t + s*4096;
    yb[(2*r)  *D_DIM + d] = fmaf(dp, ub[(2*r)  *D_DIM + d], v[s].x*invN);
    yb[(2*r+1)*D_DIM + d] = fmaf(dp, ub[(2*r+1)*D_DIM + d], v[s].y*invN);
  }
}

// ---- fused: rfft-untangle(u), rfft-untangle(K), multiply, irfft-repack ----
// Thread k in [0,8192] handles bins k and N-k of both spectra.
__global__ __launch_bounds__(256) void k_mul(const C2* __restrict__ Zu, const C2* __restrict__ ZK,
                                             C2* __restrict__ Zp, long long bstride){
  int idx = blockIdx.x*256 + threadIdx.x;         // [0, 8193*512) exact
  int d = idx & (D_DIM-1);
  int k = idx >> 9;                                // [0, 8192]
  int m = (NFFT - k) & (NFFT - 1);
  const C2* zub = Zu + (long long)blockIdx.y * bstride;
  C2*       zpb = Zp + (long long)blockIdx.y * bstride;
  C2 a  = zub[(long long)k*D_DIM + d];
  C2 bm = zub[(long long)m*D_DIM + d];
  C2 hk = ZK [(long long)k*D_DIM + d];
  C2 hm = ZK [(long long)m*D_DIM + d];
  float sw, cw; __sincosf(PI_F * (float)k / 16384.f, &sw, &cw);
  C2 w  { cw, -sw};   // e^{-i pi k/N}
  C2 wm {-cw, -sw};   // e^{-i pi (N-k)/N}
  // --- unpack u spectrum: X[k] = Ze + w*Zo ; Ze=(Z[k]+conj(Z[m]))/2, Zo=-i(Z[k]-conj(Z[m]))/2
  C2 Ze  {0.5f*(a.x + bm.x), 0.5f*(a.y - bm.y)};
  C2 Zo  {0.5f*(a.y + bm.y), -0.5f*(a.x - bm.x)};
  C2 Xk = cadd(Ze, cmul(w, Zo));
  C2 Zem {0.5f*(bm.x + a.x), 0.5f*(bm.y - a.y)};
  C2 Zom {0.5f*(bm.y + a.y), -0.5f*(bm.x - a.x)};
  C2 Xm = cadd(Zem, cmul(wm, Zom));
  // --- unpack K spectrum
  C2 KZe  {0.5f*(hk.x + hm.x), 0.5f*(hk.y - hm.y)};
  C2 KZo  {0.5f*(hk.y + hm.y), -0.5f*(hk.x - hm.x)};
  C2 Hk = cadd(KZe, cmul(w, KZo));
  C2 KZem {0.5f*(hm.x + hk.x), 0.5f*(hm.y - hk.y)};
  C2 KZom {0.5f*(hm.y + hk.y), -0.5f*(hm.x - hk.x)};
  C2 Hm = cadd(KZem, cmul(wm, KZom));
  // --- multiply
  C2 Yk = cmul(Xk, Hk);
  C2 Ym = cmul(Xm, Hm);
  // --- repack for half-length inverse: Z'[k] = E + i*O
  C2 E  {0.5f*(Yk.x + Ym.x), 0.5f*(Yk.y - Ym.y)};     // (Yk + conj(Ym))/2
  C2 T  {0.5f*(Yk.x - Ym.x), 0.5f*(Yk.y + Ym.y)};     // (Yk - conj(Ym))/2
  C2 wp { cw, sw};                                     // e^{+i pi k/N}
  C2 O = cmul(wp, T);
  zpb[(long long)k*D_DIM + d] = C2{E.x - O.y, E.y + O.x};
  if (k > 0 && k < 8192){
    C2 Em {0.5f*(Ym.x + Yk.x), 0.5f*(Ym.y - Yk.y)};
    C2 T2 {0.5f*(Ym.x - Yk.x), 0.5f*(Ym.y + Yk.y)};
    C2 wq {-cw, sw};                                   // e^{+i pi (N-k)/N}
    C2 Om = cmul(wq, T2);
    zpb[(long long)m*D_DIM + d] = C2{Em.x - Om.y, Em.y + Om.x};
  }
}

// ---------------- parameter prep: U0=conj(C)*B, U1=conj(P)*B, vecs ---------
__global__ __launch_bounds__(256) void k_prep(const float* __restrict__ B_ri, const float* __restrict__ C_ri,
                                              const float* __restrict__ P_ri,
                                              C2* __restrict__ U0, C2* __restrict__ U1, C2* __restrict__ vecs){
  int idx = blockIdx.x*256 + threadIdx.x;          // [0, 64*512)
  int n = idx >> 9;
  C2 Bnd { B_ri[2*idx], B_ri[2*idx+1] };
  C2 Cc  { C_ri[2*n], -C_ri[2*n+1] };              // conj(C[n])
  C2 Pc  { P_ri[2*n], -P_ri[2*n+1] };              // conj(P[n])
  U0[idx] = cmul(Cc, Bnd);
  U1[idx] = cmul(Pc, Bnd);
  if ((idx & (D_DIM-1)) == 0){
    C2 Pn { P_ri[2*n], P_ri[2*n+1] };
    vecs[n]       = cmul(Cc, Pn);                  // conj(C)*P
    vecs[64 + n]  = cmul(Pc, Pn);                  // conj(P)*P
  }
}

// ---------------- evaluated[l,d] * (1/L) -----------------------------------
// Block: 16 l-rows x all 512 d. Cauchy rows in LDS, k01/k11 per row, then
// the (16 x 512 x 64-mode) contraction with per-thread accumulator arrays.
// NOTE: accurate sincosf here (NOT __sincosf) — see header comment.
__global__ __launch_bounds__(256) void k_ev(const C2* __restrict__ U0, const C2* __restrict__ U1,
                                            const C2* __restrict__ vecs,
                                            const float* __restrict__ Lambda_ri,
                                            const float* __restrict__ log_step,
                                            C2* __restrict__ ev){
  __shared__ C2 sc[16][64];
  __shared__ C2 sg[16];
  __shared__ C2 salpha[16];
  __shared__ C2 sbeta[16];
  int tid = threadIdx.x;
  int l0 = blockIdx.x * 16;
  float step = expf(log_step[0]);
  if (tid < 16){
    int l = l0 + tid;
    float ang = -TWO_PI_F * (float)l / 16384.f;
    float sn, cs; sincosf(ang, &sn, &cs);          // accurate: keeps 1+Omega != 0 at l=8192
    C2 den {1.f + cs, sn};                     // 1 + Omega
    C2 num {1.f - cs, -sn};                    // 1 - Omega
    C2 r = cdiv(num, den);
    float s2 = 2.f / step;
    sg[tid] = C2{ r.x*s2, r.y*s2 };
    salpha[tid] = cdiv(C2{2.f/16384.f, 0.f}, den);   // (2/(1+Om)) * (1/L)
  }
  __syncthreads();
  for (int q = tid; q < 16*64; q += 256){
    int ll = q >> 6, n = q & 63;
    C2 lam { Lambda_ri[2*n], Lambda_ri[2*n+1] };
    C2 gm = sg[ll];
    sc[ll][n] = cdiv(C2{1.f,0.f}, C2{gm.x - lam.x, gm.y - lam.y});
  }
  __syncthreads();
  if (tid < 16){
    C2 k01{0,0}, k11{0,0};
    for (int n=0;n<64;n++){
      C2 c = sc[tid][n];
      cfma_(k01, c, vecs[n]);
      cfma_(k11, c, vecs[64+n]);
    }
    C2 denom {1.f + k11.x, k11.y};
    sbeta[tid] = cdiv(k01, denom);
  }
  __syncthreads();
  for (int d = tid; d < D_DIM; d += 256){
    C2 a0[16], a1[16];
    #pragma unroll
    for (int ll=0;ll<16;ll++){ a0[ll]=C2{0,0}; a1[ll]=C2{0,0}; }
    for (int n=0;n<64;n++){
      C2 u0 = U0[n*D_DIM + d];
      C2 u1 = U1[n*D_DIM + d];
      #pragma unroll
      for (int ll=0;ll<16;ll++){
        C2 c = sc[ll][n];
        cfma_(a0[ll], u0, c);
        cfma_(a1[ll], u1, c);
      }
    }
    #pragma unroll
    for (int ll=0;ll<16;ll++){
      C2 t = csub(a0[ll], cmul(sbeta[ll], a1[ll]));
      ev[(long long)(l0+ll)*D_DIM + d] = cmul(salpha[ll], t);
    }
  }
}

extern "C" void kernel_launch(void* const* d_in, const int* in_sizes, int n_in,
                              void* d_out, int out_size, void* d_ws, size_t ws_size,
                              hipStream_t stream){
  const float* u         = (const float*)d_in[0];
  const float* Lambda_ri = (const float*)d_in[1];
  const float* P_ri      = (const float*)d_in[2];
  const float* B_ri      = (const float*)d_in[3];
  const float* C_ri      = (const float*)d_in[4];
  const float* Dp        = (const float*)d_in[5];
  const float* log_step  = (const float*)d_in[6];
  float* y = (float*)d_out;

  const long long ND = (long long)NFFT * D_DIM;      // 8,388,608 elements
  const size_t SZ = (size_t)ND * sizeof(C2);         // 64 MiB per (b-slice) complex buffer

  // batch-chunking by available workspace: need (2*bc+1)*64MiB
  int bc = 4;
  if (ws_size < (size_t)(2*4+1)*SZ) bc = 2;
  if (ws_size < (size_t)(2*2+1)*SZ) bc = 1;
  if (ws_size < (size_t)3*SZ) return;                // cannot run

  char* base = (char*)d_ws;
  C2* RA = (C2*)base;                                // bc * 64 MiB ping
  C2* RB = (C2*)(base + (size_t)bc*SZ);              // bc * 64 MiB pong
  C2* RC = (C2*)(base + (size_t)2*bc*SZ);            // 64 MiB: Kreal then ZK
  float* Kreal = (float*)RC;                         // 32 MiB (first half of RC)
  C2* U0   = RB;                                     // transient (overwritten later)
  C2* U1   = RB + 64*D_DIM;
  C2* vecs = RB + 2*64*D_DIM;

  dim3 blk(256);

  // ---- parameter prep + evaluated (scaled by 1/L) into RA ----
  k_prep<<<dim3(128), blk, 0, stream>>>(B_ri, C_ri, P_ri, U0, U1, vecs);
  k_ev  <<<dim3(1024), blk, 0, stream>>>(U0, U1, vecs, Lambda_ri, log_step, RA);

  // ---- K path: ifft_L(ev) -> Kreal ; rfft_2L(K) packed -> ZK (in RC) ----
  k_pass16<true >  <<<dim3(2048,1), blk, 0, stream>>>(RA, RB,    1, 0LL);
  k_pass16<true >  <<<dim3(2048,1), blk, 0, stream>>>(RB, RA,   16, 0LL);
  k_pass16<true >  <<<dim3(2048,1), blk, 0, stream>>>(RA, RB,  256, 0LL);
  k_pass4_lastreal <<<dim3(8192,1), blk, 0, stream>>>(RB, Kreal);
  k_pass16_first   <<<dim3(2048,1), blk, 0, stream>>>(Kreal, RA, 0LL, 0LL);
  k_pass16<false>  <<<dim3(2048,1), blk, 0, stream>>>(RA, RB,   16, 0LL);
  k_pass16<false>  <<<dim3(2048,1), blk, 0, stream>>>(RB, RA,  256, 0LL);
  k_pass4<false>   <<<dim3(8192,1), blk, 0, stream>>>(RA, RC, 4096, 0LL);   // ZK

  // ---- u path (chunked over batch) ----
  for (int b0 = 0; b0 < 4; b0 += bc){
    const float* ub = u + (long long)b0 * ND;
    float*       yb = y + (long long)b0 * ND;
    k_pass16_first    <<<dim3(2048, bc), blk, 0, stream>>>(ub, RA, ND, ND);
    k_pass16<false>   <<<dim3(2048, bc), blk, 0, stream>>>(RA, RB,   16, ND);
    k_pass16<false>   <<<dim3(2048, bc), blk, 0, stream>>>(RB, RA,  256, ND);
    k_pass4<false>    <<<dim3(8192, bc), blk, 0, stream>>>(RA, RB, 4096, ND);   // Zu
    k_mul             <<<dim3(16386, bc), blk, 0, stream>>>(RB, RC, RA, ND);    // Z'
    k_pass16<true>    <<<dim3(2048, bc), blk, 0, stream>>>(RA, RB,    1, ND);
    k_pass16<true>    <<<dim3(2048, bc), blk, 0, stream>>>(RB, RA,   16, ND);
    k_pass16<true>    <<<dim3(2048, bc), blk, 0, stream>>>(RA, RB,  256, ND);
    k_pass4_lastyfused<<<dim3(8192, bc), blk, 0, stream>>>(RB, ub, Dp, yb, ND, ND);
  }
}

// Round 4
// 845.776 us; speedup vs baseline: 1.5477x; 1.5477x over previous
//
#include <hip/hip_runtime.h>
#include <math.h>

// S4 DPLR forward. B=4, L=16384, D=512, N=64. n_fft=2L=32768 via real-packed
// half-length (16384) complex FFTs, batched along contiguous d (no transposes).
//
// Round-3 structure:
//  * 16384-pt FFT = two sweeps (four-step 128x128): each sweep does a full
//    128-pt DFT in-block (radix-8 regs -> LDS -> radix-16 regs), 32 d-cols
//    per block, 32 KiB LDS. u-path: 5 sweeps total (pack fused into fwd
//    sweep1, y-unpack + D*u fused into inv sweep2).
//  * k_ev replaced by k_wprep (weights W[l,n'] to global) + k_ev2 (SGPR-
//    broadcast complex GEMM: W wave-uniform -> s_load; U via VGPR + prefetch).
// Round-1 lesson kept: accurate sincosf for the Omega/(1+Omega) math
// (v_sin/v_cos collapse to exact 0 at l=8192). FFT twiddles use __sincosf
// (angles < 1/4 rev, never divided).

#define D_DIM 512
#define NFFT 16384
#define TWO_PI_F 6.283185307179586f
#define PI_F 3.14159265358979323846f

struct C2 { float x, y; };

__device__ __forceinline__ C2 cmul(C2 a, C2 b){ return C2{a.x*b.x - a.y*b.y, a.x*b.y + a.y*b.x}; }
__device__ __forceinline__ C2 cadd(C2 a, C2 b){ return C2{a.x+b.x, a.y+b.y}; }
__device__ __forceinline__ C2 csub(C2 a, C2 b){ return C2{a.x-b.x, a.y-b.y}; }
__device__ __forceinline__ C2 cdiv(C2 a, C2 b){
  float inv = 1.f/(b.x*b.x + b.y*b.y);
  return C2{(a.x*b.x + a.y*b.y)*inv, (a.y*b.x - a.x*b.y)*inv};
}
__device__ __forceinline__ void cfma_(C2& acc, C2 a, C2 b){
  acc.x = fmaf(a.x, b.x, fmaf(-a.y, b.y, acc.x));
  acc.y = fmaf(a.x, b.y, fmaf( a.y, b.x, acc.y));
}

template<bool INV>
__device__ __forceinline__ void dft4(C2& a, C2& b, C2& c, C2& d){
  C2 t0 = cadd(a,c), t1 = csub(a,c), t2 = cadd(b,d), t3 = csub(b,d);
  C2 it3 = INV ? C2{-t3.y, t3.x} : C2{t3.y, -t3.x};
  a = cadd(t0,t2); c = csub(t0,t2); b = cadd(t1,it3); d = csub(t1,it3);
}

template<bool INV>
__device__ __forceinline__ void twd(C2& v, float c, float s){
  C2 w{c, INV ? s : -s};
  v = cmul(v, w);
}

// In-place 16-pt DFT (DIT 4x4). Output X[s] at v[perm16(s)], perm16(s)=4*(s&3)+(s>>2).
template<bool INV>
__device__ __forceinline__ void dft16(C2 v[16]){
  dft4<INV>(v[0], v[4], v[8],  v[12]);
  dft4<INV>(v[1], v[5], v[9],  v[13]);
  dft4<INV>(v[2], v[6], v[10], v[14]);
  dft4<INV>(v[3], v[7], v[11], v[15]);
  const float C1 = 0.9238795325112867f, S1 = 0.3826834323650898f;
  const float CQ = 0.7071067811865476f;
  const float C3 = 0.3826834323650898f, S3 = 0.9238795325112867f;
  twd<INV>(v[5],  C1,  S1);
  twd<INV>(v[9],  CQ,  CQ);
  twd<INV>(v[13], C3,  S3);
  twd<INV>(v[6],  CQ,  CQ);
  twd<INV>(v[10], 0.f, 1.f);
  twd<INV>(v[14], -CQ, CQ);
  twd<INV>(v[7],  C3,  S3);
  twd<INV>(v[11], -CQ, CQ);
  twd<INV>(v[15], -C1, -S1);
  dft4<INV>(v[0],  v[1],  v[2],  v[3]);
  dft4<INV>(v[4],  v[5],  v[6],  v[7]);
  dft4<INV>(v[8],  v[9],  v[10], v[11]);
  dft4<INV>(v[12], v[13], v[14], v[15]);
}

// 8-pt DFT, natural-order in/out. DIT radix-2: E=DFT4(even), O=DFT4(odd).
template<bool INV>
__device__ __forceinline__ void dft8(C2 v[8]){
  C2 e0=v[0], e1=v[2], e2=v[4], e3=v[6];
  C2 o0=v[1], o1=v[3], o2=v[5], o3=v[7];
  dft4<INV>(e0,e1,e2,e3);
  dft4<INV>(o0,o1,o2,o3);
  const float r = 0.7071067811865476f;
  C2 w1 = INV ? C2{r, r}    : C2{r, -r};
  C2 w2 = INV ? C2{0.f,1.f} : C2{0.f,-1.f};
  C2 w3 = INV ? C2{-r, r}   : C2{-r, -r};
  C2 t0=o0, t1=cmul(o1,w1), t2=cmul(o2,w2), t3=cmul(o3,w3);
  v[0]=cadd(e0,t0); v[4]=csub(e0,t0);
  v[1]=cadd(e1,t1); v[5]=csub(e1,t1);
  v[2]=cadd(e2,t2); v[6]=csub(e2,t2);
  v[3]=cadd(e3,t3); v[7]=csub(e3,t3);
}

// ============ Sweep 1 of four-step FFT (N=16384=128x128) ====================
// Block: a=n1 in [0,128), d-tile of 32. Reads rows a+128*j (j in [0,128)),
// does 128-pt DFT over j (radix8 -> LDS -> radix16), applies outer twiddle
// W_N^{sgn*a*k2p}, writes row k2p*128 + a.
// PACK: input is real rows (x[r]=src[2r]+i*src[2r+1], r<8192, else 0).
template<bool INV, bool PACK>
__global__ __launch_bounds__(256) void k_sweep1(const void* __restrict__ srcv, C2* __restrict__ out,
                                                long long src_bstride, long long out_bstride){
  __shared__ C2 V[128*32];
  int bx = blockIdx.x;
  int a  = bx & 127;
  int dt = bx >> 7;
  int tid = threadIdx.x;
  int dl = tid & 31;
  int g  = tid >> 5;             // [0,8)
  int d0 = dt*32 + dl;
  const float sgn = INV ? 1.f : -1.f;
  C2* ob = out + (long long)blockIdx.y * out_bstride;

  #pragma unroll
  for (int h=0; h<2; ++h){
    int j1 = 2*g + h;
    C2 v[8];
    if constexpr (PACK){
      const float* sb = (const float*)srcv + (long long)blockIdx.y * src_bstride;
      #pragma unroll
      for (int j2=0;j2<4;j2++){
        int rr = a + 128*(j1 + 16*j2);           // < 8192 exactly when j<64
        v[j2].x = sb[(long long)(2*rr)  *D_DIM + d0];
        v[j2].y = sb[(long long)(2*rr+1)*D_DIM + d0];
      }
      #pragma unroll
      for (int j2=4;j2<8;j2++) v[j2] = C2{0.f,0.f};
    } else {
      const C2* sb = (const C2*)srcv + (long long)blockIdx.y * src_bstride;
      #pragma unroll
      for (int j2=0;j2<8;j2++){
        int rr = a + 128*(j1 + 16*j2);
        v[j2] = sb[(long long)rr*D_DIM + d0];
      }
    }
    dft8<INV>(v);
    float sn, cs; __sincosf(sgn * TWO_PI_F * (float)j1 * (1.f/128.f), &sn, &cs);
    C2 w1{cs, sn}; C2 w = w1;
    #pragma unroll
    for (int k2=1;k2<8;k2++){ v[k2] = cmul(v[k2], w); w = cmul(w, w1); }
    #pragma unroll
    for (int k2=0;k2<8;k2++) V[(k2*16 + j1)*32 + dl] = v[k2];
  }
  __syncthreads();
  C2 y[16];
  #pragma unroll
  for (int j1=0;j1<16;j1++) y[j1] = V[(g*16 + j1)*32 + dl];
  dft16<INV>(y);
  // outer twiddle: W_N^{sgn*a*(g+8*k1)} chained
  float sb_, cb_; __sincosf(sgn * TWO_PI_F * (float)(a*g) * (1.f/16384.f), &sb_, &cb_);
  float ss_, cs2; __sincosf(sgn * TWO_PI_F * (float)(8*a)  * (1.f/16384.f), &ss_, &cs2);
  C2 tw{cb_, sb_}; C2 stp{cs2, ss_};
  #pragma unroll
  for (int k1=0;k1<16;k1++){
    int pidx = ((k1&3)<<2) | (k1>>2);
    C2 val = cmul(y[pidx], tw);
    int k2p = g + 8*k1;
    ob[(long long)(k2p*128 + a)*D_DIM + d0] = val;
    tw = cmul(tw, stp);
  }
}

// ============ Sweep 2: block a=k2, reads contiguous rows a*128+j, ===========
// 128-pt DFT over j, writes row a + 128*k1 (natural final order).
// OMODE 0: C2 out. 1: real part to float (Kreal). 2: y-fused unpack+scale+D*u.
template<bool INV, int OMODE>
__global__ __launch_bounds__(256) void k_sweep2(const C2* __restrict__ in, void* __restrict__ outv,
                                                const float* __restrict__ u, const float* __restrict__ Dp,
                                                long long in_bstride, long long out_bstride){
  __shared__ C2 V[128*32];
  int bx = blockIdx.x;
  int a  = bx & 127;
  int dt = bx >> 7;
  int tid = threadIdx.x;
  int dl = tid & 31;
  int g  = tid >> 5;
  int d0 = dt*32 + dl;
  const float sgn = INV ? 1.f : -1.f;
  const C2* ib = in + (long long)blockIdx.y * in_bstride;

  #pragma unroll
  for (int h=0; h<2; ++h){
    int j1 = 2*g + h;
    C2 v[8];
    #pragma unroll
    for (int j2=0;j2<8;j2++){
      int rr = a*128 + (j1 + 16*j2);
      v[j2] = ib[(long long)rr*D_DIM + d0];
    }
    dft8<INV>(v);
    float sn, cs; __sincosf(sgn * TWO_PI_F * (float)j1 * (1.f/128.f), &sn, &cs);
    C2 w1{cs, sn}; C2 w = w1;
    #pragma unroll
    for (int k2=1;k2<8;k2++){ v[k2] = cmul(v[k2], w); w = cmul(w, w1); }
    #pragma unroll
    for (int k2=0;k2<8;k2++) V[(k2*16 + j1)*32 + dl] = v[k2];
  }
  __syncthreads();
  C2 y[16];
  #pragma unroll
  for (int j1=0;j1<16;j1++) y[j1] = V[(g*16 + j1)*32 + dl];
  dft16<INV>(y);
  #pragma unroll
  for (int k1=0;k1<16;k1++){
    int pidx = ((k1&3)<<2) | (k1>>2);
    C2 val = y[pidx];
    int row = a + 128*(g + 8*k1);
    if constexpr (OMODE == 0){
      C2* ob = (C2*)outv + (long long)blockIdx.y * out_bstride;
      ob[(long long)row*D_DIM + d0] = val;
    } else if constexpr (OMODE == 1){
      float* ob = (float*)outv;
      ob[(long long)row*D_DIM + d0] = val.x;
    } else {
      if (row < 8192){                            // uniform: k1<8
        float* yb = (float*)outv + (long long)blockIdx.y * out_bstride;
        const float* ub = u + (long long)blockIdx.y * out_bstride;
        float dp = Dp[0];
        const float invN = 1.f/16384.f;
        yb[(long long)(2*row)  *D_DIM + d0] = fmaf(dp, ub[(long long)(2*row)  *D_DIM + d0], val.x*invN);
        yb[(long long)(2*row+1)*D_DIM + d0] = fmaf(dp, ub[(long long)(2*row+1)*D_DIM + d0], val.y*invN);
      }
    }
  }
}

// ---- fused: rfft-untangle(u), rfft-untangle(K), multiply, irfft-repack ----
__global__ __launch_bounds__(256) void k_mul(const C2* __restrict__ Zu, const C2* __restrict__ ZK,
                                             C2* __restrict__ Zp, long long bstride){
  int idx = blockIdx.x*256 + threadIdx.x;
  int d = idx & (D_DIM-1);
  int k = idx >> 9;                                // [0, 8192]
  int m = (NFFT - k) & (NFFT - 1);
  const C2* zub = Zu + (long long)blockIdx.y * bstride;
  C2*       zpb = Zp + (long long)blockIdx.y * bstride;
  C2 a  = zub[(long long)k*D_DIM + d];
  C2 bm = zub[(long long)m*D_DIM + d];
  C2 hk = ZK [(long long)k*D_DIM + d];
  C2 hm = ZK [(long long)m*D_DIM + d];
  float sw, cw; __sincosf(PI_F * (float)k / 16384.f, &sw, &cw);
  C2 w  { cw, -sw};
  C2 wm {-cw, -sw};
  C2 Ze  {0.5f*(a.x + bm.x), 0.5f*(a.y - bm.y)};
  C2 Zo  {0.5f*(a.y + bm.y), -0.5f*(a.x - bm.x)};
  C2 Xk = cadd(Ze, cmul(w, Zo));
  C2 Zem {0.5f*(bm.x + a.x), 0.5f*(bm.y - a.y)};
  C2 Zom {0.5f*(bm.y + a.y), -0.5f*(bm.x - a.x)};
  C2 Xm = cadd(Zem, cmul(wm, Zom));
  C2 KZe  {0.5f*(hk.x + hm.x), 0.5f*(hk.y - hm.y)};
  C2 KZo  {0.5f*(hk.y + hm.y), -0.5f*(hk.x - hm.x)};
  C2 Hk = cadd(KZe, cmul(w, KZo));
  C2 KZem {0.5f*(hm.x + hk.x), 0.5f*(hm.y - hk.y)};
  C2 KZom {0.5f*(hm.y + hk.y), -0.5f*(hm.x - hk.x)};
  C2 Hm = cadd(KZem, cmul(wm, KZom));
  C2 Yk = cmul(Xk, Hk);
  C2 Ym = cmul(Xm, Hm);
  C2 E  {0.5f*(Yk.x + Ym.x), 0.5f*(Yk.y - Ym.y)};
  C2 T  {0.5f*(Yk.x - Ym.x), 0.5f*(Yk.y + Ym.y)};
  C2 wp { cw, sw};
  C2 O = cmul(wp, T);
  zpb[(long long)k*D_DIM + d] = C2{E.x - O.y, E.y + O.x};
  if (k > 0 && k < 8192){
    C2 Em {0.5f*(Ym.x + Yk.x), 0.5f*(Ym.y - Yk.y)};
    C2 T2 {0.5f*(Ym.x - Yk.x), 0.5f*(Ym.y + Yk.y)};
    C2 wq {-cw, sw};
    C2 Om = cmul(wq, T2);
    zpb[(long long)m*D_DIM + d] = C2{Em.x - Om.y, Em.y + Om.x};
  }
}

// ---------------- parameter prep: U0=conj(C)*B, U1=conj(P)*B, vecs ---------
__global__ __launch_bounds__(256) void k_prep(const float* __restrict__ B_ri, const float* __restrict__ C_ri,
                                              const float* __restrict__ P_ri,
                                              C2* __restrict__ U0, C2* __restrict__ U1, C2* __restrict__ vecs){
  int idx = blockIdx.x*256 + threadIdx.x;          // [0, 64*512)
  int n = idx >> 9;
  C2 Bnd { B_ri[2*idx], B_ri[2*idx+1] };
  C2 Cc  { C_ri[2*n], -C_ri[2*n+1] };
  C2 Pc  { P_ri[2*n], -P_ri[2*n+1] };
  U0[idx] = cmul(Cc, Bnd);
  U1[idx] = cmul(Pc, Bnd);
  if ((idx & (D_DIM-1)) == 0){
    C2 Pn { P_ri[2*n], P_ri[2*n+1] };
    vecs[n]       = cmul(Cc, Pn);
    vecs[64 + n]  = cmul(Pc, Pn);
  }
}

// ---- weight precompute: W[l, n'] layout [l>>4][n'][l&15], n' in [0,128) ----
// W[l,n]    = alpha_l * c[l,n]          (for U0 = conj(C)*B)
// W[l,64+n] = -alpha_l*beta_l * c[l,n]  (for U1 = conj(P)*B)
__global__ __launch_bounds__(256) void k_wprep(const float* __restrict__ Lambda_ri,
                                               const float* __restrict__ log_step,
                                               const C2* __restrict__ vecs,
                                               C2* __restrict__ Wbuf){
  __shared__ C2 p01[4][64];
  __shared__ C2 p11[4][64];
  __shared__ C2 sA1[64];
  int tid = threadIdx.x;
  int li = tid & 63, q = tid >> 6;
  int l = blockIdx.x*64 + li;
  float step = expf(log_step[0]);
  float ang = -TWO_PI_F * (float)l / 16384.f;
  float sn, cs; sincosf(ang, &sn, &cs);            // accurate (l=8192 collapse!)
  C2 den{1.f+cs, sn};
  C2 num{1.f-cs, -sn};
  C2 r = cdiv(num, den);
  float s2 = 2.f/step;
  C2 gl{r.x*s2, r.y*s2};
  C2 alpha = cdiv(C2{2.f/16384.f, 0.f}, den);      // (2/(1+Om)) * (1/L)
  C2 c[16]; C2 k01{0,0}, k11{0,0};
  #pragma unroll
  for (int i=0;i<16;i++){
    int n = q*16+i;
    C2 lam{Lambda_ri[2*n], Lambda_ri[2*n+1]};
    c[i] = cdiv(C2{1.f,0.f}, C2{gl.x-lam.x, gl.y-lam.y});
    cfma_(k01, c[i], vecs[n]);
    cfma_(k11, c[i], vecs[64+n]);
  }
  p01[q][li] = k01; p11[q][li] = k11;
  __syncthreads();
  if (q==0){
    C2 s01 = cadd(cadd(p01[0][li],p01[1][li]),cadd(p01[2][li],p01[3][li]));
    C2 s11 = cadd(cadd(p11[0][li],p11[1][li]),cadd(p11[2][li],p11[3][li]));
    C2 beta = cdiv(s01, C2{1.f+s11.x, s11.y});
    C2 ab = cmul(alpha, beta);
    sA1[li] = C2{-ab.x, -ab.y};
  }
  __syncthreads();
  C2 A1 = sA1[li];
  size_t base = (size_t)(l>>4)*(128*16) + (size_t)(l&15);
  #pragma unroll
  for (int i=0;i<16;i++){
    int n = q*16+i;
    Wbuf[base + (size_t)n*16]      = cmul(alpha, c[i]);
    Wbuf[base + (size_t)(64+n)*16] = cmul(A1, c[i]);
  }
}

// ---- ev GEMM: ev[l,d] = sum_{n'} W[l,n'] * U[n',d]. Lane->d; W wave-uniform
// (expect s_load -> scalar operands). U prefetched 1 deep.
__global__ __launch_bounds__(256) void k_ev2(const C2* __restrict__ U, const C2* __restrict__ Wbuf,
                                             C2* __restrict__ ev){
  int tid = threadIdx.x;
  int tile = blockIdx.x;               // [0,1024) : 16 l-rows each
  int d0 = tid, d1 = tid + 256;
  const C2* __restrict__ Wt = Wbuf + (size_t)tile*(128*16);
  C2 acc0[16], acc1[16];
  #pragma unroll
  for (int li=0;li<16;li++){ acc0[li]=C2{0.f,0.f}; acc1[li]=C2{0.f,0.f}; }
  C2 u0 = U[d0], u1 = U[d1];
  for (int np=0; np<128; ++np){
    // prefetch next row (np=127 overreads 4KB into RB scratch: safe, unused)
    C2 nu0 = U[(size_t)(np+1)*D_DIM + d0];
    C2 nu1 = U[(size_t)(np+1)*D_DIM + d1];
    const C2* wr = Wt + (size_t)np*16;
    #pragma unroll
    for (int li=0;li<16;li++){
      C2 w = wr[li];
      cfma_(acc0[li], w, u0);
      cfma_(acc1[li], w, u1);
    }
    u0 = nu0; u1 = nu1;
  }
  long long l0 = (long long)tile*16;
  #pragma unroll
  for (int li=0;li<16;li++){
    ev[(l0+li)*D_DIM + d0] = acc0[li];
    ev[(l0+li)*D_DIM + d1] = acc1[li];
  }
}

extern "C" void kernel_launch(void* const* d_in, const int* in_sizes, int n_in,
                              void* d_out, int out_size, void* d_ws, size_t ws_size,
                              hipStream_t stream){
  const float* u         = (const float*)d_in[0];
  const float* Lambda_ri = (const float*)d_in[1];
  const float* P_ri      = (const float*)d_in[2];
  const float* B_ri      = (const float*)d_in[3];
  const float* C_ri      = (const float*)d_in[4];
  const float* Dp        = (const float*)d_in[5];
  const float* log_step  = (const float*)d_in[6];
  float* y = (float*)d_out;

  const long long ND = (long long)NFFT * D_DIM;      // 8,388,608 elements
  const size_t SZ = (size_t)ND * sizeof(C2);         // 64 MiB

  int bc = 4;
  if (ws_size < (size_t)(2*4+1)*SZ) bc = 2;
  if (ws_size < (size_t)(2*2+1)*SZ) bc = 1;
  if (ws_size < (size_t)3*SZ) return;

  char* base = (char*)d_ws;
  C2* RA = (C2*)base;                                // bc * 64 MiB ping
  C2* RB = (C2*)(base + (size_t)bc*SZ);              // bc * 64 MiB pong
  C2* RC = (C2*)(base + (size_t)2*bc*SZ);            // 64 MiB: Wbuf -> Kreal -> ZK
  C2* Wbuf  = RC;                                    // 16.7 MiB (dead after k_ev2)
  float* Kreal = (float*)RC;                         // 32 MiB (dead after K-fwd sweep1)
  C2* U0   = RB;                                     // U = [U0;U1] contiguous 512 KiB
  C2* U1   = RB + 64*D_DIM;
  C2* vecs = RB + 2*64*D_DIM;
  C2* U    = RB;

  dim3 blk(256);

  // ---- params + evaluated (scaled 1/L) into RA ----
  k_prep <<<dim3(128),  blk, 0, stream>>>(B_ri, C_ri, P_ri, U0, U1, vecs);
  k_wprep<<<dim3(256),  blk, 0, stream>>>(Lambda_ri, log_step, vecs, Wbuf);
  k_ev2  <<<dim3(1024), blk, 0, stream>>>(U, Wbuf, RA);

  // ---- K path: ifft_L(ev) -> Kreal ; rfft_2L(K) packed -> ZK (RC) ----
  k_sweep1<true,false><<<dim3(2048,1), blk, 0, stream>>>(RA, RB, 0LL, 0LL);
  k_sweep2<true,1>    <<<dim3(2048,1), blk, 0, stream>>>(RB, Kreal, nullptr, nullptr, 0LL, 0LL);
  k_sweep1<false,true><<<dim3(2048,1), blk, 0, stream>>>(Kreal, RA, 0LL, 0LL);
  k_sweep2<false,0>   <<<dim3(2048,1), blk, 0, stream>>>(RA, RC, nullptr, nullptr, 0LL, 0LL);  // ZK

  // ---- u path (chunked over batch) ----
  for (int b0 = 0; b0 < 4; b0 += bc){
    const float* ub = u + (long long)b0 * ND;
    float*       yb = y + (long long)b0 * ND;
    k_sweep1<false,true><<<dim3(2048,bc), blk, 0, stream>>>(ub, RA, ND, ND);
    k_sweep2<false,0>   <<<dim3(2048,bc), blk, 0, stream>>>(RA, RB, nullptr, nullptr, ND, ND); // Zu
    k_mul               <<<dim3(16386,bc), blk, 0, stream>>>(RB, RC, RA, ND);                  // Z'
    k_sweep1<true,false><<<dim3(2048,bc), blk, 0, stream>>>(RA, RB, ND, ND);
    k_sweep2<true,2>    <<<dim3(2048,bc), blk, 0, stream>>>(RB, yb, ub, Dp, ND, ND);           // y
  }
}

// Round 5
// 827.578 us; speedup vs baseline: 1.5818x; 1.0220x over previous
//
#include <hip/hip_runtime.h>
#include <math.h>

// S4 DPLR forward. B=4, L=16384, D=512, N=64. n_fft=2L=32768 via real-packed
// half-length (16384) complex FFTs, batched along contiguous d (no transposes).
//
// Round-5 structure:
//  * 16384-pt FFT = two sweeps (four-step 128x128), as round 3/4.
//  * u path: pack-fwd sweep1 -> fwd sweep2 (Zu) -> k_sweep1m (FUSED spectral
//    multiply + inverse sweep1; Z' never materialized) -> inv sweep2 (y-fused).
//  * k_ev2 retiled to 8 l-rows/block (2048 blocks) for occupancy: round-4 PMC
//    showed VGPR=36 (W s_load scalarization worked) but Occ=29%, VALUBusy=54%
//    -> latency-bound on cold W s_loads; more waves to hide.
// Round-1 lesson kept: accurate sincosf for Omega/(1+Omega) (v_sin/v_cos
// collapse to exact 0 at l=8192 -> NaN). FFT twiddles use __sincosf.

#define D_DIM 512
#define NFFT 16384
#define TWO_PI_F 6.283185307179586f
#define PI_F 3.14159265358979323846f

struct C2 { float x, y; };

__device__ __forceinline__ C2 cmul(C2 a, C2 b){ return C2{a.x*b.x - a.y*b.y, a.x*b.y + a.y*b.x}; }
__device__ __forceinline__ C2 cadd(C2 a, C2 b){ return C2{a.x+b.x, a.y+b.y}; }
__device__ __forceinline__ C2 csub(C2 a, C2 b){ return C2{a.x-b.x, a.y-b.y}; }
__device__ __forceinline__ C2 cdiv(C2 a, C2 b){
  float inv = 1.f/(b.x*b.x + b.y*b.y);
  return C2{(a.x*b.x + a.y*b.y)*inv, (a.y*b.x - a.x*b.y)*inv};
}
__device__ __forceinline__ void cfma_(C2& acc, C2 a, C2 b){
  acc.x = fmaf(a.x, b.x, fmaf(-a.y, b.y, acc.x));
  acc.y = fmaf(a.x, b.y, fmaf( a.y, b.x, acc.y));
}

template<bool INV>
__device__ __forceinline__ void dft4(C2& a, C2& b, C2& c, C2& d){
  C2 t0 = cadd(a,c), t1 = csub(a,c), t2 = cadd(b,d), t3 = csub(b,d);
  C2 it3 = INV ? C2{-t3.y, t3.x} : C2{t3.y, -t3.x};
  a = cadd(t0,t2); c = csub(t0,t2); b = cadd(t1,it3); d = csub(t1,it3);
}

template<bool INV>
__device__ __forceinline__ void twd(C2& v, float c, float s){
  C2 w{c, INV ? s : -s};
  v = cmul(v, w);
}

// In-place 16-pt DFT (DIT 4x4). Output X[s] at v[perm16(s)], perm16(s)=4*(s&3)+(s>>2).
template<bool INV>
__device__ __forceinline__ void dft16(C2 v[16]){
  dft4<INV>(v[0], v[4], v[8],  v[12]);
  dft4<INV>(v[1], v[5], v[9],  v[13]);
  dft4<INV>(v[2], v[6], v[10], v[14]);
  dft4<INV>(v[3], v[7], v[11], v[15]);
  const float C1 = 0.9238795325112867f, S1 = 0.3826834323650898f;
  const float CQ = 0.7071067811865476f;
  const float C3 = 0.3826834323650898f, S3 = 0.9238795325112867f;
  twd<INV>(v[5],  C1,  S1);
  twd<INV>(v[9],  CQ,  CQ);
  twd<INV>(v[13], C3,  S3);
  twd<INV>(v[6],  CQ,  CQ);
  twd<INV>(v[10], 0.f, 1.f);
  twd<INV>(v[14], -CQ, CQ);
  twd<INV>(v[7],  C3,  S3);
  twd<INV>(v[11], -CQ, CQ);
  twd<INV>(v[15], -C1, -S1);
  dft4<INV>(v[0],  v[1],  v[2],  v[3]);
  dft4<INV>(v[4],  v[5],  v[6],  v[7]);
  dft4<INV>(v[8],  v[9],  v[10], v[11]);
  dft4<INV>(v[12], v[13], v[14], v[15]);
}

// 8-pt DFT, natural-order in/out. DIT radix-2: E=DFT4(even), O=DFT4(odd).
template<bool INV>
__device__ __forceinline__ void dft8(C2 v[8]){
  C2 e0=v[0], e1=v[2], e2=v[4], e3=v[6];
  C2 o0=v[1], o1=v[3], o2=v[5], o3=v[7];
  dft4<INV>(e0,e1,e2,e3);
  dft4<INV>(o0,o1,o2,o3);
  const float r = 0.7071067811865476f;
  C2 w1 = INV ? C2{r, r}    : C2{r, -r};
  C2 w2 = INV ? C2{0.f,1.f} : C2{0.f,-1.f};
  C2 w3 = INV ? C2{-r, r}   : C2{-r, -r};
  C2 t0=o0, t1=cmul(o1,w1), t2=cmul(o2,w2), t3=cmul(o3,w3);
  v[0]=cadd(e0,t0); v[4]=csub(e0,t0);
  v[1]=cadd(e1,t1); v[5]=csub(e1,t1);
  v[2]=cadd(e2,t2); v[6]=csub(e2,t2);
  v[3]=cadd(e3,t3); v[7]=csub(e3,t3);
}

// ============ Sweep 1 of four-step FFT (N=16384=128x128) ====================
// Block: a=n1 in [0,128), d-tile of 32. Reads rows a+128*j (j in [0,128)),
// 128-pt DFT over j (radix8 -> LDS -> radix16), outer twiddle W_N^{sgn*a*k2p},
// writes row k2p*128 + a.
// PACK: input is real rows (x[r]=src[2r]+i*src[2r+1], r<8192, else 0).
template<bool INV, bool PACK>
__global__ __launch_bounds__(256) void k_sweep1(const void* __restrict__ srcv, C2* __restrict__ out,
                                                long long src_bstride, long long out_bstride){
  __shared__ C2 V[128*32];
  int bx = blockIdx.x;
  int a  = bx & 127;
  int dt = bx >> 7;
  int tid = threadIdx.x;
  int dl = tid & 31;
  int g  = tid >> 5;             // [0,8)
  int d0 = dt*32 + dl;
  const float sgn = INV ? 1.f : -1.f;
  C2* ob = out + (long long)blockIdx.y * out_bstride;

  #pragma unroll
  for (int h=0; h<2; ++h){
    int j1 = 2*g + h;
    C2 v[8];
    if constexpr (PACK){
      const float* sb = (const float*)srcv + (long long)blockIdx.y * src_bstride;
      #pragma unroll
      for (int j2=0;j2<4;j2++){
        int rr = a + 128*(j1 + 16*j2);           // < 8192 exactly when j<64
        v[j2].x = sb[(long long)(2*rr)  *D_DIM + d0];
        v[j2].y = sb[(long long)(2*rr+1)*D_DIM + d0];
      }
      #pragma unroll
      for (int j2=4;j2<8;j2++) v[j2] = C2{0.f,0.f};
    } else {
      const C2* sb = (const C2*)srcv + (long long)blockIdx.y * src_bstride;
      #pragma unroll
      for (int j2=0;j2<8;j2++){
        int rr = a + 128*(j1 + 16*j2);
        v[j2] = sb[(long long)rr*D_DIM + d0];
      }
    }
    dft8<INV>(v);
    float sn, cs; __sincosf(sgn * TWO_PI_F * (float)j1 * (1.f/128.f), &sn, &cs);
    C2 w1{cs, sn}; C2 w = w1;
    #pragma unroll
    for (int k2=1;k2<8;k2++){ v[k2] = cmul(v[k2], w); w = cmul(w, w1); }
    #pragma unroll
    for (int k2=0;k2<8;k2++) V[(k2*16 + j1)*32 + dl] = v[k2];
  }
  __syncthreads();
  C2 y[16];
  #pragma unroll
  for (int j1=0;j1<16;j1++) y[j1] = V[(g*16 + j1)*32 + dl];
  dft16<INV>(y);
  float sb_, cb_; __sincosf(sgn * TWO_PI_F * (float)(a*g) * (1.f/16384.f), &sb_, &cb_);
  float ss_, cs2; __sincosf(sgn * TWO_PI_F * (float)(8*a)  * (1.f/16384.f), &ss_, &cs2);
  C2 tw{cb_, sb_}; C2 stp{cs2, ss_};
  #pragma unroll
  for (int k1=0;k1<16;k1++){
    int pidx = ((k1&3)<<2) | (k1>>2);
    C2 val = cmul(y[pidx], tw);
    int k2p = g + 8*k1;
    ob[(long long)(k2p*128 + a)*D_DIM + d0] = val;
    tw = cmul(tw, stp);
  }
}

// ===== FUSED spectral-multiply + inverse sweep1 (u path) =====================
// For each row rr it would read from Z', instead computes Z'[rr] on the fly
// from Zu[rr], Zu[m], ZK[rr], ZK[m] (m = (16384-rr) & 16383) using the
// rfft-untangle x multiply x irfft-repack identity, then proceeds with the
// inverse 128-pt DFT + outer twiddle exactly like k_sweep1<true,false>.
// Mirror tiles pair-share between blocks a and 128-a (same dt) -> L2/L3.
__global__ __launch_bounds__(256) void k_sweep1m(const C2* __restrict__ Zu, const C2* __restrict__ ZK,
                                                 C2* __restrict__ out, long long bstride){
  __shared__ C2 V[128*32];
  int bx = blockIdx.x;
  int a  = bx & 127;
  int dt = bx >> 7;
  int tid = threadIdx.x;
  int dl = tid & 31;
  int g  = tid >> 5;
  int d0 = dt*32 + dl;
  const C2* zub = Zu + (long long)blockIdx.y * bstride;
  C2* ob = out + (long long)blockIdx.y * bstride;

  #pragma unroll
  for (int h=0; h<2; ++h){
    int j1 = 2*g + h;
    C2 v[8];
    #pragma unroll
    for (int j2=0;j2<8;j2++){
      int rr = a + 128*(j1 + 16*j2);
      int mr = (NFFT - rr) & (NFFT - 1);
      C2 zk_ = zub[(long long)rr*D_DIM + d0];
      C2 zm_ = zub[(long long)mr*D_DIM + d0];
      C2 hk_ = ZK [(long long)rr*D_DIM + d0];
      C2 hm_ = ZK [(long long)mr*D_DIM + d0];
      float sw, cw; __sincosf(PI_F * (float)rr / 16384.f, &sw, &cw);
      C2 w  { cw, -sw};    // e^{-i pi rr/16384}
      C2 wm {-cw, -sw};    // e^{-i pi mr/16384} = -conj-rotated (exact for rr=0 too)
      // untangle u spectrum at bins rr (Xk) and mr (Xm)
      C2 Ze  {0.5f*(zk_.x + zm_.x), 0.5f*(zk_.y - zm_.y)};
      C2 Zo  {0.5f*(zk_.y + zm_.y), -0.5f*(zk_.x - zm_.x)};
      C2 Xk = cadd(Ze, cmul(w, Zo));
      C2 Zem {0.5f*(zm_.x + zk_.x), 0.5f*(zm_.y - zk_.y)};
      C2 Zom {0.5f*(zm_.y + zk_.y), -0.5f*(zm_.x - zk_.x)};
      C2 Xm = cadd(Zem, cmul(wm, Zom));
      // untangle K spectrum
      C2 KZe  {0.5f*(hk_.x + hm_.x), 0.5f*(hk_.y - hm_.y)};
      C2 KZo  {0.5f*(hk_.y + hm_.y), -0.5f*(hk_.x - hm_.x)};
      C2 Hk = cadd(KZe, cmul(w, KZo));
      C2 KZem {0.5f*(hm_.x + hk_.x), 0.5f*(hm_.y - hk_.y)};
      C2 KZom {0.5f*(hm_.y + hk_.y), -0.5f*(hm_.x - hk_.x)};
      C2 Hm = cadd(KZem, cmul(wm, KZom));
      // multiply + repack for bin rr
      C2 Yk = cmul(Xk, Hk);
      C2 Ym = cmul(Xm, Hm);
      C2 E  {0.5f*(Yk.x + Ym.x), 0.5f*(Yk.y - Ym.y)};
      C2 T  {0.5f*(Yk.x - Ym.x), 0.5f*(Yk.y + Ym.y)};
      C2 wp { cw, sw};     // e^{+i pi rr/16384}
      C2 O = cmul(wp, T);
      v[j2] = C2{E.x - O.y, E.y + O.x};
    }
    dft8<true>(v);
    float sn, cs; __sincosf(TWO_PI_F * (float)j1 * (1.f/128.f), &sn, &cs);
    C2 w1{cs, sn}; C2 w = w1;
    #pragma unroll
    for (int k2=1;k2<8;k2++){ v[k2] = cmul(v[k2], w); w = cmul(w, w1); }
    #pragma unroll
    for (int k2=0;k2<8;k2++) V[(k2*16 + j1)*32 + dl] = v[k2];
  }
  __syncthreads();
  C2 y[16];
  #pragma unroll
  for (int j1=0;j1<16;j1++) y[j1] = V[(g*16 + j1)*32 + dl];
  dft16<true>(y);
  float sb_, cb_; __sincosf(TWO_PI_F * (float)(a*g) * (1.f/16384.f), &sb_, &cb_);
  float ss_, cs2; __sincosf(TWO_PI_F * (float)(8*a)  * (1.f/16384.f), &ss_, &cs2);
  C2 tw{cb_, sb_}; C2 stp{cs2, ss_};
  #pragma unroll
  for (int k1=0;k1<16;k1++){
    int pidx = ((k1&3)<<2) | (k1>>2);
    C2 val = cmul(y[pidx], tw);
    int k2p = g + 8*k1;
    ob[(long long)(k2p*128 + a)*D_DIM + d0] = val;
    tw = cmul(tw, stp);
  }
}

// ============ Sweep 2: block a=k2, reads contiguous rows a*128+j, ===========
// 128-pt DFT over j, writes row a + 128*k1 (natural final order).
// OMODE 0: C2 out. 1: real part to float (Kreal). 2: y-fused unpack+scale+D*u.
template<bool INV, int OMODE>
__global__ __launch_bounds__(256) void k_sweep2(const C2* __restrict__ in, void* __restrict__ outv,
                                                const float* __restrict__ u, const float* __restrict__ Dp,
                                                long long in_bstride, long long out_bstride){
  __shared__ C2 V[128*32];
  int bx = blockIdx.x;
  int a  = bx & 127;
  int dt = bx >> 7;
  int tid = threadIdx.x;
  int dl = tid & 31;
  int g  = tid >> 5;
  int d0 = dt*32 + dl;
  const float sgn = INV ? 1.f : -1.f;
  const C2* ib = in + (long long)blockIdx.y * in_bstride;

  #pragma unroll
  for (int h=0; h<2; ++h){
    int j1 = 2*g + h;
    C2 v[8];
    #pragma unroll
    for (int j2=0;j2<8;j2++){
      int rr = a*128 + (j1 + 16*j2);
      v[j2] = ib[(long long)rr*D_DIM + d0];
    }
    dft8<INV>(v);
    float sn, cs; __sincosf(sgn * TWO_PI_F * (float)j1 * (1.f/128.f), &sn, &cs);
    C2 w1{cs, sn}; C2 w = w1;
    #pragma unroll
    for (int k2=1;k2<8;k2++){ v[k2] = cmul(v[k2], w); w = cmul(w, w1); }
    #pragma unroll
    for (int k2=0;k2<8;k2++) V[(k2*16 + j1)*32 + dl] = v[k2];
  }
  __syncthreads();
  C2 y[16];
  #pragma unroll
  for (int j1=0;j1<16;j1++) y[j1] = V[(g*16 + j1)*32 + dl];
  dft16<INV>(y);
  #pragma unroll
  for (int k1=0;k1<16;k1++){
    int pidx = ((k1&3)<<2) | (k1>>2);
    C2 val = y[pidx];
    int row = a + 128*(g + 8*k1);
    if constexpr (OMODE == 0){
      C2* ob = (C2*)outv + (long long)blockIdx.y * out_bstride;
      ob[(long long)row*D_DIM + d0] = val;
    } else if constexpr (OMODE == 1){
      float* ob = (float*)outv;
      ob[(long long)row*D_DIM + d0] = val.x;
    } else {
      if (row < 8192){                            // uniform: k1<8
        float* yb = (float*)outv + (long long)blockIdx.y * out_bstride;
        const float* ub = u + (long long)blockIdx.y * out_bstride;
        float dp = Dp[0];
        const float invN = 1.f/16384.f;
        yb[(long long)(2*row)  *D_DIM + d0] = fmaf(dp, ub[(long long)(2*row)  *D_DIM + d0], val.x*invN);
        yb[(long long)(2*row+1)*D_DIM + d0] = fmaf(dp, ub[(long long)(2*row+1)*D_DIM + d0], val.y*invN);
      }
    }
  }
}

// ---------------- parameter prep: U0=conj(C)*B, U1=conj(P)*B, vecs ---------
__global__ __launch_bounds__(256) void k_prep(const float* __restrict__ B_ri, const float* __restrict__ C_ri,
                                              const float* __restrict__ P_ri,
                                              C2* __restrict__ U0, C2* __restrict__ U1, C2* __restrict__ vecs){
  int idx = blockIdx.x*256 + threadIdx.x;          // [0, 64*512)
  int n = idx >> 9;
  C2 Bnd { B_ri[2*idx], B_ri[2*idx+1] };
  C2 Cc  { C_ri[2*n], -C_ri[2*n+1] };
  C2 Pc  { P_ri[2*n], -P_ri[2*n+1] };
  U0[idx] = cmul(Cc, Bnd);
  U1[idx] = cmul(Pc, Bnd);
  if ((idx & (D_DIM-1)) == 0){
    C2 Pn { P_ri[2*n], P_ri[2*n+1] };
    vecs[n]       = cmul(Cc, Pn);
    vecs[64 + n]  = cmul(Pc, Pn);
  }
}

// ---- weight precompute: W tiles of 8 l-rows: [l>>3][n'][l&7], n' in [0,128) -
// W[l,n]    = alpha_l * c[l,n]          (for U0 = conj(C)*B)
// W[l,64+n] = -alpha_l*beta_l * c[l,n]  (for U1 = conj(P)*B)
__global__ __launch_bounds__(256) void k_wprep(const float* __restrict__ Lambda_ri,
                                               const float* __restrict__ log_step,
                                               const C2* __restrict__ vecs,
                                               C2* __restrict__ Wbuf){
  __shared__ C2 p01[4][64];
  __shared__ C2 p11[4][64];
  __shared__ C2 sA1[64];
  int tid = threadIdx.x;
  int li = tid & 63, q = tid >> 6;
  int l = blockIdx.x*64 + li;
  float step = expf(log_step[0]);
  float ang = -TWO_PI_F * (float)l / 16384.f;
  float sn, cs; sincosf(ang, &sn, &cs);            // accurate (l=8192 collapse!)
  C2 den{1.f+cs, sn};
  C2 num{1.f-cs, -sn};
  C2 r = cdiv(num, den);
  float s2 = 2.f/step;
  C2 gl{r.x*s2, r.y*s2};
  C2 alpha = cdiv(C2{2.f/16384.f, 0.f}, den);      // (2/(1+Om)) * (1/L)
  C2 c[16]; C2 k01{0,0}, k11{0,0};
  #pragma unroll
  for (int i=0;i<16;i++){
    int n = q*16+i;
    C2 lam{Lambda_ri[2*n], Lambda_ri[2*n+1]};
    c[i] = cdiv(C2{1.f,0.f}, C2{gl.x-lam.x, gl.y-lam.y});
    cfma_(k01, c[i], vecs[n]);
    cfma_(k11, c[i], vecs[64+n]);
  }
  p01[q][li] = k01; p11[q][li] = k11;
  __syncthreads();
  if (q==0){
    C2 s01 = cadd(cadd(p01[0][li],p01[1][li]),cadd(p01[2][li],p01[3][li]));
    C2 s11 = cadd(cadd(p11[0][li],p11[1][li]),cadd(p11[2][li],p11[3][li]));
    C2 beta = cdiv(s01, C2{1.f+s11.x, s11.y});
    C2 ab = cmul(alpha, beta);
    sA1[li] = C2{-ab.x, -ab.y};
  }
  __syncthreads();
  C2 A1 = sA1[li];
  size_t base = (size_t)(l>>3)*(128*8) + (size_t)(l&7);
  #pragma unroll
  for (int i=0;i<16;i++){
    int n = q*16+i;
    Wbuf[base + (size_t)n*8]      = cmul(alpha, c[i]);
    Wbuf[base + (size_t)(64+n)*8] = cmul(A1, c[i]);
  }
}

// ---- ev GEMM: ev[l,d] = sum_{n'} W[l,n'] * U[n',d]. Lane->d; W wave-uniform
// (s_load scalarized, VGPR=36 measured r4). 8 l-rows/block -> 2048 blocks for
// occupancy (r4: 1024 blocks -> Occ 29%, VALUBusy 54%, latency-bound).
__global__ __launch_bounds__(256) void k_ev2(const C2* __restrict__ U, const C2* __restrict__ Wbuf,
                                             C2* __restrict__ ev){
  int tid = threadIdx.x;
  int tile = blockIdx.x;               // [0,2048) : 8 l-rows each
  int d0 = tid, d1 = tid + 256;
  const C2* __restrict__ Wt = Wbuf + (size_t)tile*(128*8);
  C2 acc0[8], acc1[8];
  #pragma unroll
  for (int li=0;li<8;li++){ acc0[li]=C2{0.f,0.f}; acc1[li]=C2{0.f,0.f}; }
  C2 u0 = U[d0], u1 = U[d1];
  for (int np=0; np<128; ++np){
    // prefetch next row (np=127 overreads 4KB into RB scratch: safe, unused)
    C2 nu0 = U[(size_t)(np+1)*D_DIM + d0];
    C2 nu1 = U[(size_t)(np+1)*D_DIM + d1];
    const C2* wr = Wt + (size_t)np*8;
    #pragma unroll
    for (int li=0;li<8;li++){
      C2 w = wr[li];
      cfma_(acc0[li], w, u0);
      cfma_(acc1[li], w, u1);
    }
    u0 = nu0; u1 = nu1;
  }
  long long l0 = (long long)tile*8;
  #pragma unroll
  for (int li=0;li<8;li++){
    ev[(l0+li)*D_DIM + d0] = acc0[li];
    ev[(l0+li)*D_DIM + d1] = acc1[li];
  }
}

extern "C" void kernel_launch(void* const* d_in, const int* in_sizes, int n_in,
                              void* d_out, int out_size, void* d_ws, size_t ws_size,
                              hipStream_t stream){
  const float* u         = (const float*)d_in[0];
  const float* Lambda_ri = (const float*)d_in[1];
  const float* P_ri      = (const float*)d_in[2];
  const float* B_ri      = (const float*)d_in[3];
  const float* C_ri      = (const float*)d_in[4];
  const float* Dp        = (const float*)d_in[5];
  const float* log_step  = (const float*)d_in[6];
  float* y = (float*)d_out;

  const long long ND = (long long)NFFT * D_DIM;      // 8,388,608 elements
  const size_t SZ = (size_t)ND * sizeof(C2);         // 64 MiB

  int bc = 4;
  if (ws_size < (size_t)(2*4+1)*SZ) bc = 2;
  if (ws_size < (size_t)(2*2+1)*SZ) bc = 1;
  if (ws_size < (size_t)3*SZ) return;

  char* base = (char*)d_ws;
  C2* RA = (C2*)base;                                // bc * 64 MiB ping
  C2* RB = (C2*)(base + (size_t)bc*SZ);              // bc * 64 MiB pong
  C2* RC = (C2*)(base + (size_t)2*bc*SZ);            // 64 MiB: Wbuf -> Kreal -> ZK
  C2* Wbuf  = RC;                                    // 16.7 MiB (dead after k_ev2)
  float* Kreal = (float*)RC;                         // 32 MiB (dead after K-fwd sweep1)
  C2* U0   = RB;                                     // U = [U0;U1] contiguous 512 KiB
  C2* U1   = RB + 64*D_DIM;
  C2* vecs = RB + 2*64*D_DIM;
  C2* U    = RB;

  dim3 blk(256);

  // ---- params + evaluated (scaled 1/L) into RA ----
  k_prep <<<dim3(128),  blk, 0, stream>>>(B_ri, C_ri, P_ri, U0, U1, vecs);
  k_wprep<<<dim3(256),  blk, 0, stream>>>(Lambda_ri, log_step, vecs, Wbuf);
  k_ev2  <<<dim3(2048), blk, 0, stream>>>(U, Wbuf, RA);

  // ---- K path: ifft_L(ev) -> Kreal ; rfft_2L(K) packed -> ZK (RC) ----
  k_sweep1<true,false><<<dim3(2048,1), blk, 0, stream>>>(RA, RB, 0LL, 0LL);
  k_sweep2<true,1>    <<<dim3(2048,1), blk, 0, stream>>>(RB, Kreal, nullptr, nullptr, 0LL, 0LL);
  k_sweep1<false,true><<<dim3(2048,1), blk, 0, stream>>>(Kreal, RA, 0LL, 0LL);
  k_sweep2<false,0>   <<<dim3(2048,1), blk, 0, stream>>>(RA, RC, nullptr, nullptr, 0LL, 0LL);  // ZK

  // ---- u path (chunked over batch) ----
  for (int b0 = 0; b0 < 4; b0 += bc){
    const float* ub = u + (long long)b0 * ND;
    float*       yb = y + (long long)b0 * ND;
    k_sweep1<false,true><<<dim3(2048,bc), blk, 0, stream>>>(ub, RA, ND, ND);
    k_sweep2<false,0>   <<<dim3(2048,bc), blk, 0, stream>>>(RA, RB, nullptr, nullptr, ND, ND); // Zu
    k_sweep1m           <<<dim3(2048,bc), blk, 0, stream>>>(RB, RC, RA, ND);                   // mul+inv s1
    k_sweep2<true,2>    <<<dim3(2048,bc), blk, 0, stream>>>(RA, yb, ub, Dp, ND, ND);           // y
  }
}